// Round 1
// baseline (1612.475 us; speedup 1.0000x reference)
//
#include <hip/hip_runtime.h>
#include <hip/hip_bf16.h>

// Problem constants (fixed by setup_inputs)
#define MDIM 8192    // B*S = 4*2048
#define KDIM 4096
#define NDIM 11008   // O
#define GDIM 32      // K/128 groups
#define BM 128
#define BN 128
#define BK 32

typedef __attribute__((ext_vector_type(8))) short short8;
typedef __attribute__((ext_vector_type(4))) float f32x4;
typedef __attribute__((address_space(3))) unsigned char lds_u8;

__device__ __forceinline__ unsigned short f2bf(float f) {
    unsigned int u = __float_as_uint(f);
    u += 0x7FFFu + ((u >> 16) & 1u);   // round-to-nearest-even (inputs finite)
    return (unsigned short)(u >> 16);
}

__device__ __forceinline__ void async_ld16(const void* g, lds_u8* l) {
    __builtin_amdgcn_global_load_lds(
        (const __attribute__((address_space(1))) void*)g,
        (__attribute__((address_space(3))) void*)l, 16, 0, 0);
}

// ---------------- Prepass 1: x fp32 -> bf16 ----------------
__global__ __launch_bounds__(256) void cvt_x_kernel(const float* __restrict__ x,
                                                    unsigned short* __restrict__ xb) {
    size_t i = ((size_t)blockIdx.x * 256 + threadIdx.x) * 8;
    float4 f0 = *(const float4*)(x + i);
    float4 f1 = *(const float4*)(x + i + 4);
    union { unsigned short u[8]; uint4 v; } p;
    p.u[0] = f2bf(f0.x); p.u[1] = f2bf(f0.y); p.u[2] = f2bf(f0.z); p.u[3] = f2bf(f0.w);
    p.u[4] = f2bf(f1.x); p.u[5] = f2bf(f1.y); p.u[6] = f2bf(f1.z); p.u[7] = f2bf(f1.w);
    *(uint4*)(xb + i) = p.v;
}

// ---------------- Prepass 2: w int32 * scale -> bf16 ----------------
__global__ __launch_bounds__(256) void deq_w_kernel(const int* __restrict__ w,
                                                    const float* __restrict__ sc,
                                                    unsigned short* __restrict__ wb) {
    size_t idx  = (size_t)blockIdx.x * 256 + threadIdx.x;
    size_t base = idx * 8;                 // 8 consecutive k, all in one group (128%8==0)
    int o = (int)(base >> 12);             // /4096
    int k = (int)(base & 4095);
    float s = sc[o * GDIM + (k >> 7)];
    int4 w0 = *(const int4*)(w + base);
    int4 w1 = *(const int4*)(w + base + 4);
    union { unsigned short u[8]; uint4 v; } p;
    p.u[0] = f2bf((float)w0.x * s); p.u[1] = f2bf((float)w0.y * s);
    p.u[2] = f2bf((float)w0.z * s); p.u[3] = f2bf((float)w0.w * s);
    p.u[4] = f2bf((float)w1.x * s); p.u[5] = f2bf((float)w1.y * s);
    p.u[6] = f2bf((float)w1.z * s); p.u[7] = f2bf((float)w1.w * s);
    *(uint4*)(wb + base) = p.v;
}

// ---------------- GEMM: C[M][N] = A[M][K] * B[N][K]^T (both bf16, K-major) ----------------
// 128x128 tile, BK=32, 256 threads = 4 waves, each wave 64x64 via 4x4 MFMA 16x16x32.
// LDS layout: per row (64 B = 4 chunks of 16 B), chunk position XOR-swizzled by
// s(m) = (m>>1)&3 so ds_read_b128 frag reads land 2-way per bank-quad (free),
// while global_load_lds staging stays within the same 64 B global line per 4 lanes.
__global__ __launch_bounds__(256) void gemm_bt(const unsigned short* __restrict__ A,
                                               const unsigned short* __restrict__ B,
                                               float* __restrict__ C) {
    __shared__ unsigned short As[BM * BK];   // 8 KiB
    __shared__ unsigned short Bs[BN * BK];   // 8 KiB

    const int tid  = threadIdx.x;
    const int wave = tid >> 6;
    const int lane = tid & 63;
    const int bn = blockIdx.x, bm = blockIdx.y;
    const int row0 = bm * BM, col0 = bn * BN;

    // ---- staging mapping: wave handles chunks {2w,2w+1} of each tile ----
    // chunk = 16 rows; lane i -> row (i>>2) in chunk, 16B piece pk=(i&3);
    // the phys slot pk holds logical k-chunk ko = pk ^ s(row), s(row)=(row>>1)&3
    const int rch = lane >> 2;                       // 0..15 row in chunk
    const int ko  = (lane & 3) ^ ((lane >> 3) & 3);  // logical 8-elem k-chunk
    const unsigned short* gA0 = A + (size_t)(row0 + wave * 32 + rch) * KDIM + ko * 8;
    const unsigned short* gA1 = gA0 + (size_t)16 * KDIM;
    const unsigned short* gB0 = B + (size_t)(col0 + wave * 32 + rch) * KDIM + ko * 8;
    const unsigned short* gB1 = gB0 + (size_t)16 * KDIM;

    lds_u8* lA0 = (lds_u8*)As + wave * 2048;
    lds_u8* lA1 = lA0 + 1024;
    lds_u8* lB0 = (lds_u8*)Bs + wave * 2048;
    lds_u8* lB1 = lB0 + 1024;

    // ---- compute mapping ----
    const int q  = lane >> 4;        // k-quad: k = q*8 + j
    const int ml = lane & 15;        // m (A) / n (B) index within 16-tile
    const int sw = (ml >> 1) & 3;    // swizzle term for this row
    const int wm = wave >> 1, wn = wave & 1;

    int aoff[4], boff[4];
#pragma unroll
    for (int t = 0; t < 4; ++t) {
        aoff[t] = (wm * 64 + t * 16 + ml) * BK + ((q ^ sw) * 8);
        boff[t] = (wn * 64 + t * 16 + ml) * BK + ((q ^ sw) * 8);
    }

    f32x4 acc[4][4];
    const f32x4 z = {0.f, 0.f, 0.f, 0.f};
#pragma unroll
    for (int mt = 0; mt < 4; ++mt)
#pragma unroll
        for (int nt = 0; nt < 4; ++nt) acc[mt][nt] = z;

    for (int kt = 0; kt < KDIM / BK; ++kt) {
        __syncthreads();                       // all waves done reading previous tile
        async_ld16(gA0, lA0);
        async_ld16(gA1, lA1);
        async_ld16(gB0, lB0);
        async_ld16(gB1, lB1);
        gA0 += BK; gA1 += BK; gB0 += BK; gB1 += BK;
        __syncthreads();                       // compiler emits vmcnt(0) drain before barrier

        short8 af[4], bf[4];
#pragma unroll
        for (int t = 0; t < 4; ++t) af[t] = *(const short8*)(As + aoff[t]);
#pragma unroll
        for (int t = 0; t < 4; ++t) bf[t] = *(const short8*)(Bs + boff[t]);
#pragma unroll
        for (int mt = 0; mt < 4; ++mt)
#pragma unroll
            for (int nt = 0; nt < 4; ++nt)
                acc[mt][nt] = __builtin_amdgcn_mfma_f32_16x16x32_bf16(
                    af[mt], bf[nt], acc[mt][nt], 0, 0, 0);
    }

    // ---- epilogue: C/D layout col=lane&15, row=(lane>>4)*4+reg ----
#pragma unroll
    for (int mt = 0; mt < 4; ++mt) {
#pragma unroll
        for (int nt = 0; nt < 4; ++nt) {
            const int r0 = row0 + wm * 64 + mt * 16 + q * 4;
            const int c  = col0 + wn * 64 + nt * 16 + ml;
#pragma unroll
            for (int r = 0; r < 4; ++r)
                C[(size_t)(r0 + r) * NDIM + c] = acc[mt][nt][r];
        }
    }
}

// ---------------- Fallback (only if ws too small): naive fp32 ----------------
__global__ __launch_bounds__(256) void gemm_fallback(const float* __restrict__ X,
                                                     const int* __restrict__ W,
                                                     const float* __restrict__ S,
                                                     float* __restrict__ C) {
    int n = blockIdx.x * 256 + threadIdx.x;
    int m = blockIdx.y;
    if (n >= NDIM) return;
    const float* xr = X + (size_t)m * KDIM;
    const int*   wr = W + (size_t)n * KDIM;
    float acc = 0.f;
    for (int g = 0; g < GDIM; ++g) {
        float s = S[n * GDIM + g];
        float part = 0.f;
        for (int k = 0; k < 128; ++k)
            part += xr[g * 128 + k] * (float)wr[g * 128 + k];
        acc += part * s;
    }
    C[(size_t)m * NDIM + n] = acc;
}

extern "C" void kernel_launch(void* const* d_in, const int* in_sizes, int n_in,
                              void* d_out, int out_size, void* d_ws, size_t ws_size,
                              hipStream_t stream) {
    const float* x  = (const float*)d_in[0];
    const int*   w  = (const int*)d_in[1];
    const float* sc = (const float*)d_in[2];
    float* out = (float*)d_out;

    const size_t bytesA = (size_t)MDIM * KDIM * 2;   // 64 MiB bf16 x
    const size_t bytesB = (size_t)NDIM * KDIM * 2;   // 86 MiB bf16 dequant w

    if (ws_size >= bytesA + bytesB) {
        unsigned short* Abf = (unsigned short*)d_ws;
        unsigned short* Bbf = (unsigned short*)((char*)d_ws + bytesA);

        cvt_x_kernel<<<(MDIM * (size_t)KDIM) / 8 / 256, 256, 0, stream>>>(x, Abf);
        deq_w_kernel<<<(NDIM * (size_t)KDIM) / 8 / 256, 256, 0, stream>>>(w, sc, Bbf);
        dim3 grid(NDIM / BN, MDIM / BM);
        gemm_bt<<<grid, 256, 0, stream>>>(Abf, Bbf, out);
    } else {
        dim3 grid((NDIM + 255) / 256, MDIM);
        gemm_fallback<<<grid, 256, 0, stream>>>(x, w, sc, out);
    }
}

// Round 2
// 1479.170 us; speedup vs baseline: 1.0901x; 1.0901x over previous
//
#include <hip/hip_runtime.h>
#include <hip/hip_bf16.h>

// Problem constants (fixed by setup_inputs)
#define MDIM 8192    // B*S = 4*2048
#define KDIM 4096
#define NDIM 11008   // O
#define GDIM 32      // K/128 groups
#define BM 128
#define BN 128
#define BK 32
#define MT (MDIM / BM)   // 64 M-tiles
#define NT (NDIM / BN)   // 86 N-tiles
#define GW 16            // M-tiles per supertile column (256 blocks -> 16x16 patch)

typedef __attribute__((ext_vector_type(8))) short short8;
typedef __attribute__((ext_vector_type(4))) float f32x4;
typedef __attribute__((address_space(3))) unsigned char lds_u8;

__device__ __forceinline__ unsigned short f2bf(float f) {
    unsigned int u = __float_as_uint(f);
    u += 0x7FFFu + ((u >> 16) & 1u);   // round-to-nearest-even (inputs finite)
    return (unsigned short)(u >> 16);
}

__device__ __forceinline__ void async_ld16(const void* g, lds_u8* l) {
    __builtin_amdgcn_global_load_lds(
        (const __attribute__((address_space(1))) void*)g,
        (__attribute__((address_space(3))) void*)l, 16, 0, 0);
}

// ---------------- Prepass 1: x fp32 -> bf16 ----------------
__global__ __launch_bounds__(256) void cvt_x_kernel(const float* __restrict__ x,
                                                    unsigned short* __restrict__ xb) {
    size_t i = ((size_t)blockIdx.x * 256 + threadIdx.x) * 8;
    float4 f0 = *(const float4*)(x + i);
    float4 f1 = *(const float4*)(x + i + 4);
    union { unsigned short u[8]; uint4 v; } p;
    p.u[0] = f2bf(f0.x); p.u[1] = f2bf(f0.y); p.u[2] = f2bf(f0.z); p.u[3] = f2bf(f0.w);
    p.u[4] = f2bf(f1.x); p.u[5] = f2bf(f1.y); p.u[6] = f2bf(f1.z); p.u[7] = f2bf(f1.w);
    *(uint4*)(xb + i) = p.v;
}

// ---------------- Prepass 2: w int32 * scale -> bf16 ----------------
__global__ __launch_bounds__(256) void deq_w_kernel(const int* __restrict__ w,
                                                    const float* __restrict__ sc,
                                                    unsigned short* __restrict__ wb) {
    size_t idx  = (size_t)blockIdx.x * 256 + threadIdx.x;
    size_t base = idx * 8;                 // 8 consecutive k, all in one group (128%8==0)
    int o = (int)(base >> 12);             // /4096
    int k = (int)(base & 4095);
    float s = sc[o * GDIM + (k >> 7)];
    int4 w0 = *(const int4*)(w + base);
    int4 w1 = *(const int4*)(w + base + 4);
    union { unsigned short u[8]; uint4 v; } p;
    p.u[0] = f2bf((float)w0.x * s); p.u[1] = f2bf((float)w0.y * s);
    p.u[2] = f2bf((float)w0.z * s); p.u[3] = f2bf((float)w0.w * s);
    p.u[4] = f2bf((float)w1.x * s); p.u[5] = f2bf((float)w1.y * s);
    p.u[6] = f2bf((float)w1.z * s); p.u[7] = f2bf((float)w1.w * s);
    *(uint4*)(wb + base) = p.v;
}

// ---------------- GEMM: C[M][N] = A[M][K] * B[N][K]^T (both bf16, K-major) ----------------
// 128x128 tile, BK=32, 256 threads = 4 waves, each wave 64x64 via 4x4 MFMA 16x16x32.
// Supertile block order: 256 consecutive block ids cover a 16x16 tile patch
// (32 MiB working set ~= aggregate L2) -> tile loads hit L2, not LLC/HBM.
__global__ __launch_bounds__(256) void gemm_bt(const unsigned short* __restrict__ A,
                                               const unsigned short* __restrict__ B,
                                               float* __restrict__ C) {
    __shared__ unsigned short As[BM * BK];   // 8 KiB
    __shared__ unsigned short Bs[BN * BK];   // 8 KiB

    const int tid  = threadIdx.x;
    const int wave = tid >> 6;
    const int lane = tid & 63;

    // ---- supertile swizzle: consecutive ids walk GW M-tiles, then next N-tile ----
    const int p     = blockIdx.x;
    const int group = p / (GW * NT);
    const int rem   = p % (GW * NT);
    const int bn    = rem / GW;
    const int bm    = group * GW + rem % GW;
    const int row0 = bm * BM, col0 = bn * BN;

    // ---- staging mapping: wave handles chunks {2w,2w+1} of each tile ----
    // chunk = 16 rows; lane i -> row (i>>2) in chunk, 16B piece pk=(i&3);
    // phys slot pk holds logical k-chunk ko = pk ^ s(row), s(row)=(row>>1)&3
    const int rch = lane >> 2;                       // 0..15 row in chunk
    const int ko  = (lane & 3) ^ ((lane >> 3) & 3);  // logical 8-elem k-chunk
    const unsigned short* gA0 = A + (size_t)(row0 + wave * 32 + rch) * KDIM + ko * 8;
    const unsigned short* gA1 = gA0 + (size_t)16 * KDIM;
    const unsigned short* gB0 = B + (size_t)(col0 + wave * 32 + rch) * KDIM + ko * 8;
    const unsigned short* gB1 = gB0 + (size_t)16 * KDIM;

    lds_u8* lA0 = (lds_u8*)As + wave * 2048;
    lds_u8* lA1 = lA0 + 1024;
    lds_u8* lB0 = (lds_u8*)Bs + wave * 2048;
    lds_u8* lB1 = lB0 + 1024;

    // ---- compute mapping ----
    const int q  = lane >> 4;        // k-quad: k = q*8 + j
    const int ml = lane & 15;        // m (A) / n (B) index within 16-tile
    const int sw = (ml >> 1) & 3;    // swizzle term for this row
    const int wm = wave >> 1, wn = wave & 1;

    int aoff[4], boff[4];
#pragma unroll
    for (int t = 0; t < 4; ++t) {
        aoff[t] = (wm * 64 + t * 16 + ml) * BK + ((q ^ sw) * 8);
        boff[t] = (wn * 64 + t * 16 + ml) * BK + ((q ^ sw) * 8);
    }

    f32x4 acc[4][4];
    const f32x4 z = {0.f, 0.f, 0.f, 0.f};
#pragma unroll
    for (int mt = 0; mt < 4; ++mt)
#pragma unroll
        for (int nt = 0; nt < 4; ++nt) acc[mt][nt] = z;

    for (int kt = 0; kt < KDIM / BK; ++kt) {
        __syncthreads();                       // all waves done reading previous tile
        async_ld16(gA0, lA0);
        async_ld16(gA1, lA1);
        async_ld16(gB0, lB0);
        async_ld16(gB1, lB1);
        gA0 += BK; gA1 += BK; gB0 += BK; gB1 += BK;
        __syncthreads();                       // vmcnt(0) drain before barrier

        short8 af[4], bf[4];
#pragma unroll
        for (int t = 0; t < 4; ++t) af[t] = *(const short8*)(As + aoff[t]);
#pragma unroll
        for (int t = 0; t < 4; ++t) bf[t] = *(const short8*)(Bs + boff[t]);
#pragma unroll
        for (int mt = 0; mt < 4; ++mt)
#pragma unroll
            for (int nt = 0; nt < 4; ++nt)
                acc[mt][nt] = __builtin_amdgcn_mfma_f32_16x16x32_bf16(
                    af[mt], bf[nt], acc[mt][nt], 0, 0, 0);
    }

    // ---- epilogue: C/D layout col=lane&15, row=(lane>>4)*4+reg ----
#pragma unroll
    for (int mt = 0; mt < 4; ++mt) {
#pragma unroll
        for (int nt = 0; nt < 4; ++nt) {
            const int r0 = row0 + wm * 64 + mt * 16 + q * 4;
            const int c  = col0 + wn * 64 + nt * 16 + ml;
#pragma unroll
            for (int r = 0; r < 4; ++r)
                C[(size_t)(r0 + r) * NDIM + c] = acc[mt][nt][r];
        }
    }
}

// ---------------- Fallback (only if ws too small): naive fp32 ----------------
__global__ __launch_bounds__(256) void gemm_fallback(const float* __restrict__ X,
                                                     const int* __restrict__ W,
                                                     const float* __restrict__ S,
                                                     float* __restrict__ C) {
    int n = blockIdx.x * 256 + threadIdx.x;
    int m = blockIdx.y;
    if (n >= NDIM) return;
    const float* xr = X + (size_t)m * KDIM;
    const int*   wr = W + (size_t)n * KDIM;
    float acc = 0.f;
    for (int g = 0; g < GDIM; ++g) {
        float s = S[n * GDIM + g];
        float part = 0.f;
        for (int k = 0; k < 128; ++k)
            part += xr[g * 128 + k] * (float)wr[g * 128 + k];
        acc += part * s;
    }
    C[(size_t)m * NDIM + n] = acc;
}

extern "C" void kernel_launch(void* const* d_in, const int* in_sizes, int n_in,
                              void* d_out, int out_size, void* d_ws, size_t ws_size,
                              hipStream_t stream) {
    const float* x  = (const float*)d_in[0];
    const int*   w  = (const int*)d_in[1];
    const float* sc = (const float*)d_in[2];
    float* out = (float*)d_out;

    const size_t bytesA = (size_t)MDIM * KDIM * 2;   // 64 MiB bf16 x
    const size_t bytesB = (size_t)NDIM * KDIM * 2;   // 86 MiB bf16 dequant w

    if (ws_size >= bytesA + bytesB) {
        unsigned short* Abf = (unsigned short*)d_ws;
        unsigned short* Bbf = (unsigned short*)((char*)d_ws + bytesA);

        cvt_x_kernel<<<(MDIM * (size_t)KDIM) / 8 / 256, 256, 0, stream>>>(x, Abf);
        deq_w_kernel<<<(NDIM * (size_t)KDIM) / 8 / 256, 256, 0, stream>>>(w, sc, Bbf);
        gemm_bt<<<MT * NT, 256, 0, stream>>>(Abf, Bbf, out);
    } else {
        dim3 grid((NDIM + 255) / 256, MDIM);
        gemm_fallback<<<grid, 256, 0, stream>>>(x, w, sc, out);
    }
}